// Round 11
// baseline (71.612 us; speedup 1.0000x reference)
//
// R11: single fused kernel — per-block ballot-pack of weights into LDS
// (removes the serial pack pre-kernel + its launch gap), then the R10-passed
// main loop byte-unchanged. d_ws no longer used.
// Poison ledger: 2-row dual-chain unroll = confirmed no-store poison (R7);
// ballot-pack alone = untested until now; everything else in this file has
// passed on hardware (R10, absmax 0.0).
#include <hip/hip_runtime.h>
#include <stdint.h>

typedef unsigned long long u64;

// LDS layout (u64 words):
//   [0..511]   w1 packed: row r (0..127), word j (0..3); bit l = w1[r][l*4+j] < 0
//   [512..639] w2 packed: row r (0..63), word j (0..1); bit l = w2[r][j*64+l] < 0
//   [640]      w3 packed: bit l = w3[l] < 0
// Weights treated as nonzero (normal*0.1). Hidden activations ternary
// (exact-zero preact ~5%/elem) -> nonzero masks. x rows take the exact
// ternary slow path only when they contain an exact 0.0f (product-ballot
// detect; false positives harmless).

__global__ __launch_bounds__(256) void xnor_fused(
    const float* __restrict__ x,
    const float* __restrict__ w1, const float* __restrict__ b1,
    const float* __restrict__ w2, const float* __restrict__ b2,
    const float* __restrict__ w3, const float* __restrict__ b3,
    float* __restrict__ out, int B)
{
    __shared__ u64 wp[641];

    const int lane = threadIdx.x & 63;
    const int wib  = threadIdx.x >> 6;   // 0..3
    const int wpb  = blockDim.x >> 6;    // 4

    // ---- Stage 1: ballot-pack weights into LDS (one-time, L2-resident reads).
    // w1: wave w packs rows w*32 .. w*32+31 (4 waves cover 128 rows).
    for (int r = wib * 32; r < wib * 32 + 32; ++r) {
        const float4 v = *reinterpret_cast<const float4*>(w1 + r * 256 + (lane << 2));
        const u64 s0 = __ballot(v.x < 0.0f);
        const u64 s1 = __ballot(v.y < 0.0f);
        const u64 s2 = __ballot(v.z < 0.0f);
        const u64 s3 = __ballot(v.w < 0.0f);
        if (lane == 0) {
            wp[r * 4 + 0] = s0; wp[r * 4 + 1] = s1;
            wp[r * 4 + 2] = s2; wp[r * 4 + 3] = s3;
        }
    }
    // w2: waves 0-1 pack 32 rows each (natural order, 2 words/row); wave 2: w3.
    if (wib < 2) {
        for (int r = wib * 32; r < wib * 32 + 32; ++r) {
            const float a = w2[r * 128 + lane];
            const float b = w2[r * 128 + 64 + lane];
            const u64 s0 = __ballot(a < 0.0f);
            const u64 s1 = __ballot(b < 0.0f);
            if (lane == 0) { wp[512 + r * 2] = s0; wp[512 + r * 2 + 1] = s1; }
        }
    } else if (wib == 2) {
        const u64 s = __ballot(w3[lane] < 0.0f);
        if (lane == 0) wp[640] = s;
    }
    __syncthreads();

    // ---- Stage 2: per-lane weight fragments from LDS (one-time).
    // lane l owns w1 rows l and l+64, and w2 row l.
    u64 w1a[4], w1b[4], w2r[2];
    #pragma unroll
    for (int j = 0; j < 4; ++j) {
        w1a[j] = wp[lane * 4 + j];
        w1b[j] = wp[(lane + 64) * 4 + j];
    }
    w2r[0] = wp[512 + lane * 2 + 0];
    w2r[1] = wp[512 + lane * 2 + 1];
    const u64 w3w = wp[640];
    const float b1a = b1[lane], b1b = b1[lane + 64];
    const float b2v = b2[lane];
    const float b3v = b3[0];

    // ---- Stage 3: main loop (byte-identical logic to the R10-passed build).
    const long long gw = (long long)blockIdx.x * wpb + wib;
    const long long nw = (long long)gridDim.x * wpb;

    for (long long row = gw; row < B; row += nw) {
        // 1 KB coalesced row load: lane l takes elements l*4 .. l*4+3.
        const float4 xv = *reinterpret_cast<const float4*>(x + row * 256 + (lane << 2));

        // Sign ballots (word j, bit l <-> element l*4+j, matching w1 layout).
        const u64 sx0 = __ballot(xv.x < 0.0f);
        const u64 sx1 = __ballot(xv.y < 0.0f);
        const u64 sx2 = __ballot(xv.z < 0.0f);
        const u64 sx3 = __ballot(xv.w < 0.0f);

        // Zero-detect: prod==0 iff some element is +/-0.0f (no overflow at
        // |x|<~6; underflow false-positives just take the exact path).
        const float prod = xv.x * xv.y * xv.z * xv.w;
        const u64 zb = __ballot(prod == 0.0f);

        int pa, pb, nzx;
        if (zb == 0ull) {
            // Fast path (~always): all 256 elements nonzero.
            nzx = 256;
            pa = __popcll(sx0 ^ w1a[0]) + __popcll(sx1 ^ w1a[1])
               + __popcll(sx2 ^ w1a[2]) + __popcll(sx3 ^ w1a[3]);
            pb = __popcll(sx0 ^ w1b[0]) + __popcll(sx1 ^ w1b[1])
               + __popcll(sx2 ^ w1b[2]) + __popcll(sx3 ^ w1b[3]);
        } else {
            // Exact ternary path (rare): mask out zero elements.
            const u64 mx0 = __ballot(xv.x != 0.0f);
            const u64 mx1 = __ballot(xv.y != 0.0f);
            const u64 mx2 = __ballot(xv.z != 0.0f);
            const u64 mx3 = __ballot(xv.w != 0.0f);
            nzx = __popcll(mx0) + __popcll(mx1) + __popcll(mx2) + __popcll(mx3);
            pa = __popcll((sx0 ^ w1a[0]) & mx0) + __popcll((sx1 ^ w1a[1]) & mx1)
               + __popcll((sx2 ^ w1a[2]) & mx2) + __popcll((sx3 ^ w1a[3]) & mx3);
            pb = __popcll((sx0 ^ w1b[0]) & mx0) + __popcll((sx1 ^ w1b[1]) & mx1)
               + __popcll((sx2 ^ w1b[2]) & mx2) + __popcll((sx3 ^ w1b[3]) & mx3);
        }

        const float ta = (float)(nzx - 2 * pa) + b1a;   // pre-activation row 'lane'
        const float tb = (float)(nzx - 2 * pb) + b1b;   // pre-activation row 'lane+64'

        // h1 ternary: word 0 = rows 0..63, word 1 = rows 64..127 (natural order).
        const u64 s1_0 = __ballot(ta < 0.0f);
        const u64 s1_1 = __ballot(tb < 0.0f);
        const u64 m1_0 = __ballot(ta != 0.0f);
        const u64 m1_1 = __ballot(tb != 0.0f);
        const int nz1 = __popcll(m1_0) + __popcll(m1_1);

        // Layer 2: row 'lane' of w2.
        const int p2 = __popcll((s1_0 ^ w2r[0]) & m1_0)
                     + __popcll((s1_1 ^ w2r[1]) & m1_1);
        const float t2 = (float)(nz1 - 2 * p2) + b2v;

        // h2 ternary (64 values, natural order).
        const u64 s2 = __ballot(t2 < 0.0f);
        const u64 m2 = __ballot(t2 != 0.0f);
        const int nz2 = __popcll(m2);

        // Layer 3 + sigmoid (wave-uniform).
        const int p3 = __popcll((s2 ^ w3w) & m2);
        const float t3 = (float)(nz2 - 2 * p3) + b3v;
        const float res = 1.0f / (1.0f + __expf(-t3));
        if (lane == 0) out[row] = res;
    }
}

extern "C" void kernel_launch(void* const* d_in, const int* in_sizes, int n_in,
                              void* d_out, int out_size, void* d_ws, size_t ws_size,
                              hipStream_t stream)
{
    const float* x  = (const float*)d_in[0];
    const float* w1 = (const float*)d_in[1];
    const float* b1 = (const float*)d_in[2];
    const float* w2 = (const float*)d_in[3];
    const float* b2 = (const float*)d_in[4];
    const float* w3 = (const float*)d_in[5];
    const float* b3 = (const float*)d_in[6];
    float* out = (float*)d_out;
    const int B = in_sizes[0] / 256;

    // Single fused dispatch: 2048 blocks * 4 waves = 8192 waves,
    // 32 rows per wave, grid-strided. Weights packed per-block in LDS.
    const int blocks = 2048;
    xnor_fused<<<blocks, 256, 0, stream>>>(x, w1, b1, w2, b2, w3, b3, out, B);
}